// Round 9
// baseline (122.061 us; speedup 1.0000x reference)
//
#include <hip/hip_runtime.h>
#include <hip/hip_fp16.h>

constexpr int EMB = 256;
constexpr int RELDIMS = 512;
constexpr float FEPS = 1e-6f;
constexpr int ROWS = 8;     // rows per wave
constexpr int WPB  = 4;     // waves per block

typedef float f4 __attribute__((ext_vector_type(4)));

__device__ __forceinline__ float ftanh(float x) {
    x = fminf(15.f, fmaxf(-15.f, x));
    float t = __expf(2.f * x);
    return (t - 1.f) * __builtin_amdgcn_rcpf(t + 1.f);
}

// ---------- precompute: packed fp16 {ct, wp1} per (rel, dim); word = h*EMB+d ----------
__global__ __launch_bounds__(256) void boxe_pre(
    const float* __restrict__ rel, int n_rel, unsigned int* __restrict__ pre)
{
    const int r    = (blockIdx.x * blockDim.x + threadIdx.x) >> 6;
    const int lane = threadIdx.x & 63;
    if (r >= n_rel) return;
    const float* __restrict__ rrow = rel + (long)r * (4 * EMB + 2);
    const int d0 = lane * 4;

    float c0[4], c1[4], w0[4], w1[4];
    *(float4*)c0 = *(const float4*)(rrow + d0);
    *(float4*)c1 = *(const float4*)(rrow + EMB + d0);
    *(float4*)w0 = *(const float4*)(rrow + 2 * EMB + d0);
    *(float4*)w1 = *(const float4*)(rrow + 3 * EMB + d0);
    const float bs0 = rrow[4 * EMB + 0];
    const float bs1 = rrow[4 * EMB + 1];

    float wa0[4], wa1[4], ls0 = 0.f, ls1 = 0.f;
#pragma unroll
    for (int j = 0; j < 4; ++j) {
        wa0[j] = fabsf(w0[j]); wa1[j] = fabsf(w1[j]);
        ls0 += __logf(fmaxf(wa0[j], FEPS));
        ls1 += __logf(fmaxf(wa1[j], FEPS));
    }
#pragma unroll
    for (int off = 32; off >= 1; off >>= 1) {
        ls0 += __shfl_xor(ls0, off, 64);
        ls1 += __shfl_xor(ls1, off, 64);
    }
    const float g0 = __expf(ls0 * (1.f / (float)EMB));
    const float g1 = __expf(ls1 * (1.f / (float)EMB));
    const float e0 = (bs0 > 0.f) ? bs0 : (__expf(bs0) - 1.f);
    const float e1 = (bs1 > 0.f) ? bs1 : (__expf(bs1) - 1.f);
    const float s0 = (1.f + e0) / fmaxf(g0, FEPS);
    const float s1 = (1.f + e1) / fmaxf(g1, FEPS);

    unsigned int* __restrict__ prow = pre + (long)r * RELDIMS;
    unsigned int pk[4];
#pragma unroll
    for (int j = 0; j < 4; ++j) {
        __half2 h2 = __floats2half2_rn(ftanh(c0[j]), ftanh(wa0[j] * s0) + 1.f);
        pk[j] = *(unsigned int*)&h2;
    }
    *(uint4*)(prow + d0) = make_uint4(pk[0], pk[1], pk[2], pk[3]);
#pragma unroll
    for (int j = 0; j < 4; ++j) {
        __half2 h2 = __floats2half2_rn(ftanh(c1[j]), ftanh(wa1[j] * s1) + 1.f);
        pk[j] = *(unsigned int*)&h2;
    }
    *(uint4*)(prow + EMB + d0) = make_uint4(pk[0], pk[1], pk[2], pk[3]);
}

// ---------- main: lane owns 8 dims of one head; 8 rows/wave; 4-buffer prefetch;
// ---------- batched bit-reversal reduction (10 cross-lane ops for all 8 rows) ----------
__global__ __launch_bounds__(256, 4) void boxe_main(
    const float* __restrict__ head, const int* __restrict__ rid,
    const float* __restrict__ tail, const unsigned int* __restrict__ pre,
    float* __restrict__ out)
{
    const int wave = blockIdx.x * WPB + (threadIdx.x >> 6);
    const int lane = threadIdx.x & 63;
    const int bb   = wave * ROWS;

    // lane l: half = l>>5; head row gives pos (low lanes) / bump (high lanes)
    const int fidx = lane * 8;
    const int tidx = (lane ^ 32) * 8;   // swap pos<->bump in the tail row

    int ridv[ROWS];
    {
        int4 ra = *(const int4*)(rid + bb);
        int4 rb = *(const int4*)(rid + bb + 4);
        ridv[0] = ra.x; ridv[1] = ra.y; ridv[2] = ra.z; ridv[3] = ra.w;
        ridv[4] = rb.x; ridv[5] = rb.y; ridv[6] = rb.z; ridv[7] = rb.w;
    }

    f4    hbuf[4][2], tbuf[4][2];
    uint4 pbuf[4][2];

#define LOADROW(slot, i_)                                                     \
    {                                                                         \
        const float* hrow = head + (size_t)(bb + (i_)) * RELDIMS;             \
        const float* trow = tail + (size_t)(bb + (i_)) * RELDIMS;             \
        const unsigned int* prow = pre + (size_t)ridv[(i_)] * RELDIMS;        \
        hbuf[slot][0] = *(const f4*)(hrow + fidx);                            \
        hbuf[slot][1] = *(const f4*)(hrow + fidx + 4);                        \
        tbuf[slot][0] = *(const f4*)(trow + tidx);                            \
        tbuf[slot][1] = *(const f4*)(trow + tidx + 4);                        \
        pbuf[slot][0] = *(const uint4*)(prow + fidx);                         \
        pbuf[slot][1] = *(const uint4*)(prow + fidx + 4);                     \
    }

    // prologue: rows 0,1,2 in flight (prefetch distance 3)
    LOADROW(0, 0)
    LOADROW(1, 1)
    LOADROW(2, 2)

    float acc[ROWS];

#pragma unroll
    for (int i = 0; i < ROWS; ++i) {
        const int cur = i & 3;
        if (i + 3 < ROWS) {
            const int nxt = (i + 3) & 3;
            LOADROW(nxt, i + 3)
        }

        float h[8], t[8];
        unsigned int pw[8];
        *(f4*)(h)     = hbuf[cur][0]; *(f4*)(h + 4) = hbuf[cur][1];
        *(f4*)(t)     = tbuf[cur][0]; *(f4*)(t + 4) = tbuf[cur][1];
        *(uint4*)(pw) = pbuf[cur][0]; *(uint4*)(pw + 4) = pbuf[cur][1];

        float a = 0.f;
#pragma unroll
        for (int j = 0; j < 8; ++j) {
            float2 cw = __half22float2(*(__half2*)&pw[j]);
            float ct = cw.x, wp1 = cw.y;
            float bt  = ftanh(h[j] + t[j]);
            float cd  = fabsf(bt - ct);
            float wv  = wp1 - 1.f;
            float inv = __builtin_amdgcn_rcpf(wp1);
            float kap = 0.5f * wv * (wp1 - inv);
            float d   = (cd <= 0.5f * wv) ? (cd * inv) : fmaf(cd, wp1, -kap);
            a = fmaf(d, d, a);
        }
        acc[i] = a;   // no cross-lane ops inside the loop
    }
#undef LOADROW

    // batched reduction: all 8 rows reduced with 10 cross-lane ops.
    // After step k, a lane holds rows selected by its low lane bits (bit-reversed).
    const bool p0 = lane & 1, p1 = lane & 2, p2 = lane & 4;
    float u[4];
#pragma unroll
    for (int j = 0; j < 4; ++j) {
        float send = p0 ? acc[j] : acc[j + 4];
        float keep = p0 ? acc[j + 4] : acc[j];
        u[j] = keep + __shfl_xor(send, 1, 64);
    }
    float v2[2];
#pragma unroll
    for (int j = 0; j < 2; ++j) {
        float send = p1 ? u[j] : u[j + 2];
        float keep = p1 ? u[j + 2] : u[j];
        v2[j] = keep + __shfl_xor(send, 2, 64);
    }
    {
        float send = p2 ? v2[0] : v2[1];
        float keep = p2 ? v2[1] : v2[0];
        float s = keep + __shfl_xor(send, 4, 64);
        s += __shfl_xor(s, 8, 64);
        s += __shfl_xor(s, 16, 64);          // s = half-sum for row bitrev3(lane&7)
        float sq = sqrtf(s);
        float other = __shfl_xor(sq, 32, 64); // same row, other head
        if (lane < 8) {
            const int r = ((lane & 1) << 2) | (lane & 2) | ((lane >> 2) & 1);
            out[bb + r] = -(sq + other);
        }
    }
}

// ---------- fallback: R1 fused kernel ----------
__device__ __forceinline__ float dist2_term(float wabs, float scale, float c, float bm) {
    float w   = ftanh(wabs * scale);
    float ctv = ftanh(c);
    float bt  = ftanh(bm);
    float cd  = fabsf(bt - ctv);
    float wp1 = w + 1.f;
    float inv = __builtin_amdgcn_rcpf(wp1);
    float kappa = 0.5f * w * (wp1 - inv);
    float dist = (cd <= 0.5f * w) ? (cd * inv) : fmaf(cd, wp1, -kappa);
    return dist * dist;
}

__global__ __launch_bounds__(256) void boxe_fused(
    const float* __restrict__ head, const int* __restrict__ rid,
    const float* __restrict__ tail, const float* __restrict__ rel,
    float* __restrict__ out, int batch)
{
    const int b    = (int)(((size_t)blockIdx.x * blockDim.x + threadIdx.x) >> 6);
    const int lane = threadIdx.x & 63;
    if (b >= batch) return;
    const long r = rid[b];
    const float* __restrict__ rrow = rel  + r * (long)(4 * EMB + 2);
    const float* __restrict__ hrow = head + (long)b * RELDIMS;
    const float* __restrict__ trow = tail + (long)b * RELDIMS;
    const int d0 = lane * 4;
    float hp[4], hb[4], tp[4], tb[4], c0[4], c1[4], w0[4], w1[4];
    *(float4*)hp = *(const float4*)(hrow + d0);
    *(float4*)hb = *(const float4*)(hrow + EMB + d0);
    *(float4*)tp = *(const float4*)(trow + d0);
    *(float4*)tb = *(const float4*)(trow + EMB + d0);
    *(float4*)c0 = *(const float4*)(rrow + d0);
    *(float4*)c1 = *(const float4*)(rrow + EMB + d0);
    *(float4*)w0 = *(const float4*)(rrow + 2 * EMB + d0);
    *(float4*)w1 = *(const float4*)(rrow + 3 * EMB + d0);
    const float bs0 = rrow[4 * EMB + 0];
    const float bs1 = rrow[4 * EMB + 1];
    float wa0[4], wa1[4], ls0 = 0.f, ls1 = 0.f;
#pragma unroll
    for (int j = 0; j < 4; ++j) {
        wa0[j] = fabsf(w0[j]); wa1[j] = fabsf(w1[j]);
        ls0 += __logf(fmaxf(wa0[j], FEPS)); ls1 += __logf(fmaxf(wa1[j], FEPS));
    }
#pragma unroll
    for (int off = 32; off >= 1; off >>= 1) {
        ls0 += __shfl_xor(ls0, off, 64); ls1 += __shfl_xor(ls1, off, 64);
    }
    const float g0 = __expf(ls0 * (1.f / 256.f)), g1 = __expf(ls1 * (1.f / 256.f));
    const float e0 = (bs0 > 0.f) ? bs0 : (__expf(bs0) - 1.f);
    const float e1 = (bs1 > 0.f) ? bs1 : (__expf(bs1) - 1.f);
    const float s0 = (1.f + e0) / fmaxf(g0, FEPS);
    const float s1 = (1.f + e1) / fmaxf(g1, FEPS);
    float acc0 = 0.f, acc1 = 0.f;
#pragma unroll
    for (int j = 0; j < 4; ++j) {
        acc0 += dist2_term(wa0[j], s0, c0[j], hp[j] + tb[j]);
        acc1 += dist2_term(wa1[j], s1, c1[j], tp[j] + hb[j]);
    }
#pragma unroll
    for (int off = 32; off >= 1; off >>= 1) {
        acc0 += __shfl_xor(acc0, off, 64); acc1 += __shfl_xor(acc1, off, 64);
    }
    if (lane == 0) out[b] = -(sqrtf(acc0) + sqrtf(acc1));
}

extern "C" void kernel_launch(void* const* d_in, const int* in_sizes, int n_in,
                              void* d_out, int out_size, void* d_ws, size_t ws_size,
                              hipStream_t stream) {
    const float* head = (const float*)d_in[0];
    const int*   rid  = (const int*)d_in[1];
    const float* tail = (const float*)d_in[2];
    const float* rel  = (const float*)d_in[3];
    float* out = (float*)d_out;

    const int batch = out_size;                       // 131072
    const int n_rel = in_sizes[3] / (4 * EMB + 2);    // 1024
    const size_t need = (size_t)n_rel * RELDIMS * sizeof(unsigned int);  // 2 MB

    if (ws_size >= need && batch % (WPB * ROWS) == 0) {
        unsigned int* pre = (unsigned int*)d_ws;
        boxe_pre<<<(n_rel + 3) / 4, 256, 0, stream>>>(rel, n_rel, pre);
        const int blocks = batch / (WPB * ROWS);      // 4096
        boxe_main<<<blocks, 256, 0, stream>>>(head, rid, tail, pre, out);
    } else {
        const int blocks = (batch + 3) / 4;
        boxe_fused<<<blocks, 256, 0, stream>>>(head, rid, tail, rel, out, batch);
    }
}

// Round 10
// 106.353 us; speedup vs baseline: 1.1477x; 1.1477x over previous
//
#include <hip/hip_runtime.h>
#include <hip/hip_fp16.h>

constexpr int EMB = 256;
constexpr int RELDIMS = 512;
constexpr float FEPS = 1e-6f;
constexpr int ROWS = 4;     // rows per wave (TLP probe: 8 -> 4)
constexpr int WPB  = 4;     // waves per block

typedef float f4 __attribute__((ext_vector_type(4)));

__device__ __forceinline__ float ftanh(float x) {
    x = fminf(15.f, fmaxf(-15.f, x));
    float t = __expf(2.f * x);
    return (t - 1.f) * __builtin_amdgcn_rcpf(t + 1.f);
}

// ---------- precompute: packed fp16 {ct, wp1} per (rel, dim); word = h*EMB+d ----------
__global__ __launch_bounds__(256) void boxe_pre(
    const float* __restrict__ rel, int n_rel, unsigned int* __restrict__ pre)
{
    const int r    = (blockIdx.x * blockDim.x + threadIdx.x) >> 6;
    const int lane = threadIdx.x & 63;
    if (r >= n_rel) return;
    const float* __restrict__ rrow = rel + (long)r * (4 * EMB + 2);
    const int d0 = lane * 4;

    float c0[4], c1[4], w0[4], w1[4];
    *(float4*)c0 = *(const float4*)(rrow + d0);
    *(float4*)c1 = *(const float4*)(rrow + EMB + d0);
    *(float4*)w0 = *(const float4*)(rrow + 2 * EMB + d0);
    *(float4*)w1 = *(const float4*)(rrow + 3 * EMB + d0);
    const float bs0 = rrow[4 * EMB + 0];
    const float bs1 = rrow[4 * EMB + 1];

    float wa0[4], wa1[4], ls0 = 0.f, ls1 = 0.f;
#pragma unroll
    for (int j = 0; j < 4; ++j) {
        wa0[j] = fabsf(w0[j]); wa1[j] = fabsf(w1[j]);
        ls0 += __logf(fmaxf(wa0[j], FEPS));
        ls1 += __logf(fmaxf(wa1[j], FEPS));
    }
#pragma unroll
    for (int off = 32; off >= 1; off >>= 1) {
        ls0 += __shfl_xor(ls0, off, 64);
        ls1 += __shfl_xor(ls1, off, 64);
    }
    const float g0 = __expf(ls0 * (1.f / (float)EMB));
    const float g1 = __expf(ls1 * (1.f / (float)EMB));
    const float e0 = (bs0 > 0.f) ? bs0 : (__expf(bs0) - 1.f);
    const float e1 = (bs1 > 0.f) ? bs1 : (__expf(bs1) - 1.f);
    const float s0 = (1.f + e0) / fmaxf(g0, FEPS);
    const float s1 = (1.f + e1) / fmaxf(g1, FEPS);

    unsigned int* __restrict__ prow = pre + (long)r * RELDIMS;
    unsigned int pk[4];
#pragma unroll
    for (int j = 0; j < 4; ++j) {
        __half2 h2 = __floats2half2_rn(ftanh(c0[j]), ftanh(wa0[j] * s0) + 1.f);
        pk[j] = *(unsigned int*)&h2;
    }
    *(uint4*)(prow + d0) = make_uint4(pk[0], pk[1], pk[2], pk[3]);
#pragma unroll
    for (int j = 0; j < 4; ++j) {
        __half2 h2 = __floats2half2_rn(ftanh(c1[j]), ftanh(wa1[j] * s1) + 1.f);
        pk[j] = *(unsigned int*)&h2;
    }
    *(uint4*)(prow + EMB + d0) = make_uint4(pk[0], pk[1], pk[2], pk[3]);
}

// ---------- main: lane owns 8 dims of one head; 4 rows/wave; 3-buffer prefetch ----------
__global__ __launch_bounds__(256, 4) void boxe_main(
    const float* __restrict__ head, const int* __restrict__ rid,
    const float* __restrict__ tail, const unsigned int* __restrict__ pre,
    float* __restrict__ out)
{
    const int wave = blockIdx.x * WPB + (threadIdx.x >> 6);
    const int lane = threadIdx.x & 63;
    const int b0   = wave * ROWS;

    // lane l: half = l>>5; head row gives pos (low lanes) / bump (high lanes)
    const int fidx = lane * 8;
    const int tidx = (lane ^ 32) * 8;   // swap pos<->bump in the tail row

    int ridv[ROWS];
    {
        int4 ra = *(const int4*)(rid + b0);
        ridv[0] = ra.x; ridv[1] = ra.y; ridv[2] = ra.z; ridv[3] = ra.w;
    }

    f4    hbuf[3][2], tbuf[3][2];
    uint4 pbuf[3][2];

#define LOADROW(slot, i_)                                                     \
    {                                                                         \
        const float* hrow = head + (size_t)(b0 + (i_)) * RELDIMS;             \
        const float* trow = tail + (size_t)(b0 + (i_)) * RELDIMS;             \
        const unsigned int* prow = pre + (size_t)ridv[(i_)] * RELDIMS;        \
        hbuf[slot][0] = *(const f4*)(hrow + fidx);                            \
        hbuf[slot][1] = *(const f4*)(hrow + fidx + 4);                        \
        tbuf[slot][0] = *(const f4*)(trow + tidx);                            \
        tbuf[slot][1] = *(const f4*)(trow + tidx + 4);                        \
        pbuf[slot][0] = *(const uint4*)(prow + fidx);                         \
        pbuf[slot][1] = *(const uint4*)(prow + fidx + 4);                     \
    }

    // prologue: rows 0,1 in flight (prefetch distance 2)
    LOADROW(0, 0)
    LOADROW(1, 1)

#pragma unroll
    for (int i = 0; i < ROWS; ++i) {
        const int cur = i % 3;
        if (i + 2 < ROWS) {
            const int nxt = (i + 2) % 3;
            LOADROW(nxt, i + 2)
        }

        float h[8], t[8];
        unsigned int pw[8];
        *(f4*)(h)     = hbuf[cur][0]; *(f4*)(h + 4) = hbuf[cur][1];
        *(f4*)(t)     = tbuf[cur][0]; *(f4*)(t + 4) = tbuf[cur][1];
        *(uint4*)(pw) = pbuf[cur][0]; *(uint4*)(pw + 4) = pbuf[cur][1];

        float acc = 0.f;
#pragma unroll
        for (int j = 0; j < 8; ++j) {
            float2 cw = __half22float2(*(__half2*)&pw[j]);
            float ct = cw.x, wp1 = cw.y;
            float bt  = ftanh(h[j] + t[j]);
            float cd  = fabsf(bt - ct);
            float wv  = wp1 - 1.f;
            float inv = __builtin_amdgcn_rcpf(wp1);
            float kap = 0.5f * wv * (wp1 - inv);
            float d   = (cd <= 0.5f * wv) ? (cd * inv) : fmaf(cd, wp1, -kap);
            acc = fmaf(d, d, acc);
        }
        // butterfly within each 32-lane half (both heads reduce simultaneously)
#pragma unroll
        for (int off = 16; off >= 1; off >>= 1)
            acc += __shfl_xor(acc, off, 64);
        float other = __shfl_xor(acc, 32, 64);
        if (lane == 0) out[b0 + i] = -(sqrtf(acc) + sqrtf(other));
    }
#undef LOADROW
}

// ---------- fallback: R1 fused kernel ----------
__device__ __forceinline__ float dist2_term(float wabs, float scale, float c, float bm) {
    float w   = ftanh(wabs * scale);
    float ctv = ftanh(c);
    float bt  = ftanh(bm);
    float cd  = fabsf(bt - ctv);
    float wp1 = w + 1.f;
    float inv = __builtin_amdgcn_rcpf(wp1);
    float kappa = 0.5f * w * (wp1 - inv);
    float dist = (cd <= 0.5f * w) ? (cd * inv) : fmaf(cd, wp1, -kappa);
    return dist * dist;
}

__global__ __launch_bounds__(256) void boxe_fused(
    const float* __restrict__ head, const int* __restrict__ rid,
    const float* __restrict__ tail, const float* __restrict__ rel,
    float* __restrict__ out, int batch)
{
    const int b    = (int)(((size_t)blockIdx.x * blockDim.x + threadIdx.x) >> 6);
    const int lane = threadIdx.x & 63;
    if (b >= batch) return;
    const long r = rid[b];
    const float* __restrict__ rrow = rel  + r * (long)(4 * EMB + 2);
    const float* __restrict__ hrow = head + (long)b * RELDIMS;
    const float* __restrict__ trow = tail + (long)b * RELDIMS;
    const int d0 = lane * 4;
    float hp[4], hb[4], tp[4], tb[4], c0[4], c1[4], w0[4], w1[4];
    *(float4*)hp = *(const float4*)(hrow + d0);
    *(float4*)hb = *(const float4*)(hrow + EMB + d0);
    *(float4*)tp = *(const float4*)(trow + d0);
    *(float4*)tb = *(const float4*)(trow + EMB + d0);
    *(float4*)c0 = *(const float4*)(rrow + d0);
    *(float4*)c1 = *(const float4*)(rrow + EMB + d0);
    *(float4*)w0 = *(const float4*)(rrow + 2 * EMB + d0);
    *(float4*)w1 = *(const float4*)(rrow + 3 * EMB + d0);
    const float bs0 = rrow[4 * EMB + 0];
    const float bs1 = rrow[4 * EMB + 1];
    float wa0[4], wa1[4], ls0 = 0.f, ls1 = 0.f;
#pragma unroll
    for (int j = 0; j < 4; ++j) {
        wa0[j] = fabsf(w0[j]); wa1[j] = fabsf(w1[j]);
        ls0 += __logf(fmaxf(wa0[j], FEPS)); ls1 += __logf(fmaxf(wa1[j], FEPS));
    }
#pragma unroll
    for (int off = 32; off >= 1; off >>= 1) {
        ls0 += __shfl_xor(ls0, off, 64); ls1 += __shfl_xor(ls1, off, 64);
    }
    const float g0 = __expf(ls0 * (1.f / 256.f)), g1 = __expf(ls1 * (1.f / 256.f));
    const float e0 = (bs0 > 0.f) ? bs0 : (__expf(bs0) - 1.f);
    const float e1 = (bs1 > 0.f) ? bs1 : (__expf(bs1) - 1.f);
    const float s0 = (1.f + e0) / fmaxf(g0, FEPS);
    const float s1 = (1.f + e1) / fmaxf(g1, FEPS);
    float acc0 = 0.f, acc1 = 0.f;
#pragma unroll
    for (int j = 0; j < 4; ++j) {
        acc0 += dist2_term(wa0[j], s0, c0[j], hp[j] + tb[j]);
        acc1 += dist2_term(wa1[j], s1, c1[j], tp[j] + hb[j]);
    }
#pragma unroll
    for (int off = 32; off >= 1; off >>= 1) {
        acc0 += __shfl_xor(acc0, off, 64); acc1 += __shfl_xor(acc1, off, 64);
    }
    if (lane == 0) out[b] = -(sqrtf(acc0) + sqrtf(acc1));
}

extern "C" void kernel_launch(void* const* d_in, const int* in_sizes, int n_in,
                              void* d_out, int out_size, void* d_ws, size_t ws_size,
                              hipStream_t stream) {
    const float* head = (const float*)d_in[0];
    const int*   rid  = (const int*)d_in[1];
    const float* tail = (const float*)d_in[2];
    const float* rel  = (const float*)d_in[3];
    float* out = (float*)d_out;

    const int batch = out_size;                       // 131072
    const int n_rel = in_sizes[3] / (4 * EMB + 2);    // 1024
    const size_t need = (size_t)n_rel * RELDIMS * sizeof(unsigned int);  // 2 MB

    if (ws_size >= need && batch % (WPB * ROWS) == 0) {
        unsigned int* pre = (unsigned int*)d_ws;
        boxe_pre<<<(n_rel + 3) / 4, 256, 0, stream>>>(rel, n_rel, pre);
        const int blocks = batch / (WPB * ROWS);      // 8192
        boxe_main<<<blocks, 256, 0, stream>>>(head, rid, tail, pre, out);
    } else {
        const int blocks = (batch + 3) / 4;
        boxe_fused<<<blocks, 256, 0, stream>>>(head, rid, tail, rel, out, batch);
    }
}